// Round 5
// baseline (23.345 us; speedup 1.0000x reference)
//
#include <hip/hip_runtime.h>

#define SIZE 512
#define NTRI 512

#pragma clang fp contract(off)

// d_ws layout (float4 units): rec[t*4+q] for q=0..3 at [0,2048);
// verts[t*2+q] at [2048,3072); zmin at float index 12288.
#define WS_VERT4 2048
#define WS_ZMIN  12288

__device__ __forceinline__ float lin_at(int i) {
    // Replicates jnp.linspace(-1, 1, 512): for i < 511,
    // s = i/511 (f32 correctly-rounded div), out = (-1)*(1-s) + 1*s = s - (1-s).
    // Endpoint i == 511 is exactly 1.0.
    if (i == SIZE - 1) return 1.0f;
    float s = __fdiv_rn((float)i, 511.0f);
    float u = 1.0f - s;
    return s - u;
}

// Bit-exact reference epilogue for the winning triangle (true division, exact op order).
__device__ __forceinline__ float4 shade(const float* __restrict__ tris, int bi,
                                        float px, float py) {
#pragma clang fp contract(off)
    if (bi < 0) return make_float4(0.0f, 0.0f, 0.0f, 0.0f);
    const float* p = tris + bi * 9;
    float a0 = p[0], a1 = p[1], a2 = p[2];
    float b0 = p[3], b1 = p[4], b2 = p[5];
    float c0 = p[6], c1 = p[7], c2 = p[8];
    float w = (b0 - a0) * (c1 - a1) - (b1 - a1) * (c0 - a0);
    float sw = (fabsf(w) > 1e-8f) ? w : 1.0f;
    float dax = a0 - px, day = a1 - py;
    float dbx = b0 - px, dby = b1 - py;
    float dcx = c0 - px, dcy = c1 - py;
    float pAB = dax * dby - day * dbx;
    float pBC = dbx * dcy - dby * dcx;
    float w1 = __fdiv_rn(pAB, sw);
    float w2 = __fdiv_rn(pBC, sw);
    float w3 = 1.0f - w1 - w2;
    float x = (w1 * a0 + w2 * b0) + w3 * c0;
    float y = (w1 * a1 + w2 * b1) + w3 * c1;
    float z = (w1 * a2 + w2 * b2) + w3 * c2;
    return make_float4(x, y, z, 1.0f);
}

__global__ __launch_bounds__(512) void setup_kernel(const float* __restrict__ tris,
                                                    float* __restrict__ ws) {
#pragma clang fp contract(off)
    __shared__ float sred[8];
    const int t = threadIdx.x;
    const float* p = tris + t * 9;
    float a0 = p[0], a1 = p[1], a2 = p[2];
    float b0 = p[3], b1 = p[4], b2 = p[5];
    float c0 = p[6], c1 = p[7], c2 = p[8];

    float w = (b0 - a0) * (c1 - a1) - (b1 - a1) * (c0 - a0);
    bool vw = fabsf(w) > 1e-8f;
    float sw = vw ? w : 1.0f;
    float rsw = __fdiv_rn(1.0f, sw);
    float k1 = (a2 - c2) * rsw;
    float k2 = (b2 - c2) * rsw;

    float cAB = a0 * b1 - a1 * b0, gxAB = a1 - b1, gyAB = b0 - a0;
    float cBC = b0 * c1 - b1 * c0, gxBC = b1 - c1, gyBC = c0 - b0;
    float cCA = c0 * a1 - c1 * a0, gxCA = c1 - a1, gyCA = a0 - c0;
    float zc = c2 + k1 * cAB + k2 * cBC;
    float zx = k1 * gxAB + k2 * gxBC;
    float zy = k1 * gyAB + k2 * gyBC;

    float lox = fminf(fminf(a0, b0), c0);
    float loy = fminf(fminf(a1, b1), c1);
    float hix = fmaxf(fmaxf(a0, b0), c0);
    float hiy = fmaxf(fmaxf(a1, b1), c1);
    int bb0 = (int)((fminf(fmaxf(lox, -1.0f), 1.0f) + 1.0f) * 0.5f * 512.0f);
    int bb1 = (int)((fminf(fmaxf(loy, -1.0f), 1.0f) + 1.0f) * 0.5f * 512.0f);
    int bb2 = (int)((fminf(fmaxf(hix, -1.0f), 1.0f) + 1.0f) * 0.5f * 512.0f);
    int bb3 = (int)((fminf(fmaxf(hiy, -1.0f), 1.0f) + 1.0f) * 0.5f * 512.0f);

    // Winding/validity cull baked into an empty bbox (fails every tile intersect).
    bool cand0 = vw && (w > -1e-4f);
    if (!cand0) { bb0 = 0; bb2 = 0; }
    unsigned bx = (unsigned)bb0 | ((unsigned)bb2 << 16);
    unsigned by = (unsigned)bb1 | ((unsigned)bb3 << 16);

    float4* f4 = (float4*)ws;
    f4[t * 4 + 0] = make_float4(cAB, gxAB, gyAB, cBC);
    f4[t * 4 + 1] = make_float4(gxBC, gyBC, cCA, gxCA);
    f4[t * 4 + 2] = make_float4(gyCA, zc, zx, zy);
    f4[t * 4 + 3] = make_float4(__uint_as_float(bx), __uint_as_float(by), 0.0f, 0.0f);
    f4[WS_VERT4 + t * 2]     = make_float4(a0, a1, b0, b1);
    f4[WS_VERT4 + t * 2 + 1] = make_float4(c0, c1, 0.0f, 0.0f);

    // Global zmin = min over all tris[..., 2] (min: exact, no rounding).
    float zt = fminf(a2, fminf(b2, c2));
    for (int off = 32; off; off >>= 1) zt = fminf(zt, __shfl_xor(zt, off));
    if ((t & 63) == 0) sred[t >> 6] = zt;
    __syncthreads();
    if (t == 0) {
        float zmin = sred[0];
        for (int g = 1; g < 8; ++g) zmin = fminf(zmin, sred[g]);
        ws[WS_ZMIN] = zmin;
    }
}

__global__ __launch_bounds__(128) void render_kernel(const float* __restrict__ tris,
                                                     const float* __restrict__ ws,
                                                     float* __restrict__ out) {
#pragma clang fp contract(off)
    __shared__ float4 szp[NTRI];   // zc, zx, zy, bitcast(t)   (all classes, compacted)
    __shared__ int4   sbb[NTRI];   // int bbox                 (classes IP, EX)
    __shared__ float4 sv0[NTRI];   // a0, a1, b0, b1           (class EX)
    __shared__ float2 sv1[NTRI];   // c0, c1                   (class EX)
    __shared__ unsigned long long smA[8], smB[8], smC[8];

    const int tx = threadIdx.x;          // 0..15 -> j offset
    const int ty = threadIdx.y;          // 0..7
    const int tid = ty * 16 + tx;
    const int lane = tid & 63, wv = tid >> 6;
    const unsigned long long lt = (1ull << lane) - 1ull;

    const int i0 = blockIdx.y * 16;
    const int j0 = blockIdx.x * 16;

    const float pxlo = lin_at(i0), pxhi = lin_at(i0 + 15);
    const float pylo = lin_at(j0), pyhi = lin_at(j0 + 15);

    const float4* f4 = (const float4*)ws;
    const float zmin = ws[WS_ZMIN];

    // ---- phase 1: 4 precomputed records/thread: cull + classify ----
    float4 vzp[4];
    unsigned vbx[4], vby[4];
    bool vIF[4], vIP[4], vEX[4];

#pragma unroll
    for (int r = 0; r < 4; ++r) {
        const int t = tid + r * 128;
        float4 q0 = f4[t * 4 + 0];
        float4 q1 = f4[t * 4 + 1];
        float4 q2 = f4[t * 4 + 2];
        float4 q3 = f4[t * 4 + 3];
        unsigned bx = __float_as_uint(q3.x), by = __float_as_uint(q3.y);
        int bb0 = (int)(bx & 0xffffu), bb2 = (int)(bx >> 16);
        int bb1 = (int)(by & 0xffffu), bb3 = (int)(by >> 16);
        vbx[r] = bx; vby[r] = by;
        vzp[r] = make_float4(q2.y, q2.z, q2.w, __int_as_float(t));

        bool cand = (bb0 < i0 + 16) && (bb2 > i0) && (bb1 < j0 + 16) && (bb3 > j0);

        // Edge-vs-tile rect: E = c + gx*px + gy*py (linear).
        // max over rect < -1e-3 -> cull; min over rect > +1e-3 -> edge positive
        // at every tile pixel. Guard 1e-3 >> ~1.5e-5 fp discrepancy bound.
        bool allIn = false;
        if (cand) {
            float x0 = q0.y * pxlo, x1 = q0.y * pxhi;
            float y0 = q0.z * pylo, y1 = q0.z * pyhi;
            float mx = q0.x + fmaxf(x0, x1) + fmaxf(y0, y1);
            float mn = q0.x + fminf(x0, x1) + fminf(y0, y1);
            cand = mx >= -1e-3f;
            allIn = mn > 1e-3f;
            x0 = q1.x * pxlo; x1 = q1.x * pxhi;
            y0 = q1.y * pylo; y1 = q1.y * pyhi;
            mx = q0.w + fmaxf(x0, x1) + fmaxf(y0, y1);
            mn = q0.w + fminf(x0, x1) + fminf(y0, y1);
            cand = cand && (mx >= -1e-3f);
            allIn = allIn && (mn > 1e-3f);
            x0 = q1.w * pxlo; x1 = q1.w * pxhi;
            y0 = q2.x * pylo; y1 = q2.x * pyhi;
            mx = q1.z + fmaxf(x0, x1) + fmaxf(y0, y1);
            mn = q1.z + fminf(x0, x1) + fminf(y0, y1);
            cand = cand && (mx >= -1e-3f);
            allIn = allIn && (mn > 1e-3f);
        }

        bool full = (bb0 <= i0) && (bb2 >= i0 + 16) && (bb1 <= j0) && (bb3 >= j0 + 16);
        vIF[r] = cand && allIn && full;
        vIP[r] = cand && allIn && !full;
        vEX[r] = cand && !allIn;

        unsigned long long mA = __ballot(vIF[r]);
        unsigned long long mB = __ballot(vIP[r]);
        unsigned long long mC = __ballot(vEX[r]);
        if (lane == 0) { smA[r * 2 + wv] = mA; smB[r * 2 + wv] = mB; smC[r * 2 + wv] = mC; }
    }
    __syncthreads();

    // ---- phase 2: ordered scatter into 3 compacted segments ----
    int bA[8], bB[8], bC[8], c = 0;
#pragma unroll
    for (int g = 0; g < 8; ++g) { bA[g] = c; c += __popcll(smA[g]); }
    const int cntA = c;
#pragma unroll
    for (int g = 0; g < 8; ++g) { bB[g] = c; c += __popcll(smB[g]); }
    const int cntB = c;
#pragma unroll
    for (int g = 0; g < 8; ++g) { bC[g] = c; c += __popcll(smC[g]); }
    const int cntC = c;

#pragma unroll
    for (int r = 0; r < 4; ++r) {
        if (vIF[r] || vIP[r] || vEX[r]) {
            const int g = r * 2 + wv;
            const int t = tid + r * 128;
            int pos;
            if (vIF[r])      pos = bA[g] + __popcll(smA[g] & lt);
            else if (vIP[r]) pos = bB[g] + __popcll(smB[g] & lt);
            else             pos = bC[g] + __popcll(smC[g] & lt);

            szp[pos] = vzp[r];
            if (!vIF[r]) {
                unsigned bx = vbx[r], by = vby[r];
                sbb[pos] = make_int4((int)(bx & 0xffffu), (int)(by & 0xffffu),
                                     (int)(bx >> 16), (int)(by >> 16));
            }
            if (vEX[r]) {
                float4 v01 = f4[WS_VERT4 + t * 2];
                float4 v2c = f4[WS_VERT4 + t * 2 + 1];
                sv0[pos] = v01;
                sv1[pos] = make_float2(v2c.x, v2c.y);
            }
        }
    }
    __syncthreads();

    // ---- phase 3: per-pixel loop, 2 pixels/thread, 3 segments ----
    const int j  = j0 + tx;
    const int iA = i0 + ty;
    const int iB = iA + 8;
    const float pxA = lin_at(iA);
    const float pxB = lin_at(iB);
    const float py  = lin_at(j);

    float bestA = zmin, bestB = zmin;
    float bfA = __int_as_float(-1), bfB = __int_as_float(-1);

    // S1: interior + full bbox: z-plane only.
#pragma unroll 4
    for (int k = 0; k < cntA; ++k) {
        float4 zp = szp[k];
        float base = fmaf(zp.z, py, zp.x);
        float zA = fmaf(zp.y, pxA, base);
        float zB = fmaf(zp.y, pxB, base);
        if (zA >= bestA) { bestA = zA; bfA = zp.w; }
        if (zB >= bestB) { bestB = zB; bfB = zp.w; }
    }
    // S2: interior + partial bbox.
#pragma unroll 4
    for (int k = cntA; k < cntB; ++k) {
        float4 zp = szp[k];
        int4 bb = sbb[k];
        float base = fmaf(zp.z, py, zp.x);
        float zA = fmaf(zp.y, pxA, base);
        float zB = fmaf(zp.y, pxB, base);
        bool inJ = (j >= bb.y) & (j < bb.w);
        bool inA = (iA >= bb.x) & (iA < bb.z) & inJ;
        bool inB = (iB >= bb.x) & (iB < bb.z) & inJ;
        if (inA & (zA >= bestA)) { bestA = zA; bfA = zp.w; }
        if (inB & (zB >= bestB)) { bestB = zB; bfB = zp.w; }
    }
    // S3: exact edge evaluation (reference op order) + bbox.
#pragma unroll 2
    for (int k = cntB; k < cntC; ++k) {
        float4 zp = szp[k];
        float4 f0 = sv0[k];
        float2 f1 = sv1[k];
        int4 bb = sbb[k];
        float day = f0.y - py, dby = f0.w - py, dcy = f1.y - py;
        float base = fmaf(zp.z, py, zp.x);
        bool inJ = (j >= bb.y) & (j < bb.w);
        {
            float dax = f0.x - pxA, dbx = f0.z - pxA, dcx = f1.x - pxA;
            float pAB = dax * dby - day * dbx;
            float pBC = dbx * dcy - dby * dcx;
            float pCA = dcx * day - dcy * dax;
            bool cov = (pAB > 0.0f) & (pBC > 0.0f) & (pCA > 0.0f) &
                       (iA >= bb.x) & (iA < bb.z) & inJ;
            float zA = fmaf(zp.y, pxA, base);
            if (cov & (zA >= bestA)) { bestA = zA; bfA = zp.w; }
        }
        {
            float dax = f0.x - pxB, dbx = f0.z - pxB, dcx = f1.x - pxB;
            float pAB = dax * dby - day * dbx;
            float pBC = dbx * dcy - dby * dcx;
            float pCA = dcx * day - dcy * dax;
            bool cov = (pAB > 0.0f) & (pBC > 0.0f) & (pCA > 0.0f) &
                       (iB >= bb.x) & (iB < bb.z) & inJ;
            float zB = fmaf(zp.y, pxB, base);
            if (cov & (zB >= bestB)) { bestB = zB; bfB = zp.w; }
        }
    }

    // ---- epilogue: bit-exact shade of winners ----
    ((float4*)out)[iA * SIZE + j] = shade(tris, __float_as_int(bfA), pxA, py);
    ((float4*)out)[iB * SIZE + j] = shade(tris, __float_as_int(bfB), pxB, py);
}

extern "C" void kernel_launch(void* const* d_in, const int* in_sizes, int n_in,
                              void* d_out, int out_size, void* d_ws, size_t ws_size,
                              hipStream_t stream) {
    const float* tris = (const float*)d_in[0];
    float* ws = (float*)d_ws;
    float* out = (float*)d_out;
    setup_kernel<<<1, 512, 0, stream>>>(tris, ws);
    dim3 grid(SIZE / 16, SIZE / 16, 1);
    dim3 block(16, 8, 1);
    render_kernel<<<grid, block, 0, stream>>>(tris, ws, out);
}

// Round 6
// 16.306 us; speedup vs baseline: 1.4317x; 1.4317x over previous
//
#include <hip/hip_runtime.h>

#define SIZE 512
#define NTRI 512

#pragma clang fp contract(off)

__device__ __forceinline__ float lin_at(int i) {
    // Replicates jnp.linspace(-1, 1, 512): for i < 511,
    // s = i/511 (f32 correctly-rounded div), out = (-1)*(1-s) + 1*s = s - (1-s).
    // Endpoint i == 511 is exactly 1.0.
    if (i == SIZE - 1) return 1.0f;
    float s = __fdiv_rn((float)i, 511.0f);
    float u = 1.0f - s;
    return s - u;
}

// Bit-exact reference epilogue for the winning triangle (true division, exact op order).
__device__ __forceinline__ float4 shade(const float* __restrict__ tris, int bi,
                                        float px, float py) {
#pragma clang fp contract(off)
    if (bi < 0) return make_float4(0.0f, 0.0f, 0.0f, 0.0f);
    const float* p = tris + bi * 9;
    float a0 = p[0], a1 = p[1], a2 = p[2];
    float b0 = p[3], b1 = p[4], b2 = p[5];
    float c0 = p[6], c1 = p[7], c2 = p[8];
    float w = (b0 - a0) * (c1 - a1) - (b1 - a1) * (c0 - a0);
    float sw = (fabsf(w) > 1e-8f) ? w : 1.0f;
    float dax = a0 - px, day = a1 - py;
    float dbx = b0 - px, dby = b1 - py;
    float dcx = c0 - px, dcy = c1 - py;
    float pAB = dax * dby - day * dbx;
    float pBC = dbx * dcy - dby * dcx;
    float w1 = __fdiv_rn(pAB, sw);
    float w2 = __fdiv_rn(pBC, sw);
    float w3 = 1.0f - w1 - w2;
    float x = (w1 * a0 + w2 * b0) + w3 * c0;
    float y = (w1 * a1 + w2 * b1) + w3 * c1;
    float z = (w1 * a2 + w2 * b2) + w3 * c2;
    return make_float4(x, y, z, 1.0f);
}

__global__ __launch_bounds__(256) void render_kernel(const float* __restrict__ tris,
                                                     float* __restrict__ out) {
#pragma clang fp contract(off)
    __shared__ float4 szp[NTRI];   // zc, zx, zy, bitcast(t)   (all classes, compacted)
    __shared__ int4   sbb[NTRI];   // int bbox                 (classes IP, EX)
    __shared__ float4 sv0[NTRI];   // a0, a1, b0, b1           (class EX)
    __shared__ float2 sv1[NTRI];   // c0, c1                   (class EX)
    __shared__ unsigned long long smA[8], smB[8], smC[8];
    __shared__ float sred[4];

    const int tx = threadIdx.x;          // 0..15 -> j offset
    const int ty = threadIdx.y;          // 0..15 -> i offset
    const int tid = ty * 16 + tx;        // 0..255
    const int lane = tid & 63, wv = tid >> 6;
    const unsigned long long lt = (1ull << lane) - 1ull;

    const int i0 = blockIdx.y * 16;
    const int j0 = blockIdx.x * 16;

    const float pxlo = lin_at(i0), pxhi = lin_at(i0 + 15);
    const float pylo = lin_at(j0), pyhi = lin_at(j0 + 15);

    // ---- phase 1: 2 tris/thread: preprocess, cull, classify (registers) ----
    float va0[2], va1[2], va2[2], vb0[2], vb1[2], vb2[2], vc0[2], vc1[2], vc2[2], vsw[2];
    int   vx0[2], vy0[2], vx1[2], vy1[2];
    bool  vIF[2], vIP[2], vEX[2];

    float zm = 1e30f;
#pragma unroll
    for (int r = 0; r < 2; ++r) {
        const int t = tid + r * 256;
        const float* p = tris + t * 9;
        float a0 = p[0], a1 = p[1], a2 = p[2];
        float b0 = p[3], b1 = p[4], b2 = p[5];
        float c0 = p[6], c1 = p[7], c2 = p[8];
        va0[r] = a0; va1[r] = a1; va2[r] = a2;
        vb0[r] = b0; vb1[r] = b1; vb2[r] = b2;
        vc0[r] = c0; vc1[r] = c1; vc2[r] = c2;

        zm = fminf(zm, fminf(a2, fminf(b2, c2)));

        float w = (b0 - a0) * (c1 - a1) - (b1 - a1) * (c0 - a0);
        bool vw = fabsf(w) > 1e-8f;
        vsw[r] = vw ? w : 1.0f;

        float lox = fminf(fminf(a0, b0), c0);
        float loy = fminf(fminf(a1, b1), c1);
        float hix = fmaxf(fmaxf(a0, b0), c0);
        float hiy = fmaxf(fmaxf(a1, b1), c1);
        int bb0 = (int)((fminf(fmaxf(lox, -1.0f), 1.0f) + 1.0f) * 0.5f * 512.0f);
        int bb1 = (int)((fminf(fmaxf(loy, -1.0f), 1.0f) + 1.0f) * 0.5f * 512.0f);
        int bb2 = (int)((fminf(fmaxf(hix, -1.0f), 1.0f) + 1.0f) * 0.5f * 512.0f);
        int bb3 = (int)((fminf(fmaxf(hiy, -1.0f), 1.0f) + 1.0f) * 0.5f * 512.0f);
        vx0[r] = bb0; vy0[r] = bb1; vx1[r] = bb2; vy1[r] = bb3;

        // Winding cull (pAB+pBC+pCA == w algebraically) + bbox-vs-tile cull.
        bool cand = vw && (w > -1e-4f) &&
                    (bb0 < i0 + 16) && (bb2 > i0) &&
                    (bb1 < j0 + 16) && (bb3 > j0);

        // Edge-vs-tile rect: linear edge fn E = c + gx*px + gy*py.
        // max over rect < -1e-3  -> certainly no covered pixel (cull).
        // min over rect > +1e-3  -> edge certainly positive at every tile pixel.
        // Guard 1e-3 >> 1.5e-5 bound on |computed_ref - linear| fp discrepancy.
        bool allIn = false;
        if (cand) {
            float cAB = a0 * b1 - a1 * b0, gxAB = a1 - b1, gyAB = b0 - a0;
            float cBC = b0 * c1 - b1 * c0, gxBC = b1 - c1, gyBC = c0 - b0;
            float cCA = c0 * a1 - c1 * a0, gxCA = c1 - a1, gyCA = a0 - c0;
            float x0, x1, y0, y1, mx, mn;
            x0 = gxAB * pxlo; x1 = gxAB * pxhi; y0 = gyAB * pylo; y1 = gyAB * pyhi;
            mx = cAB + fmaxf(x0, x1) + fmaxf(y0, y1);
            mn = cAB + fminf(x0, x1) + fminf(y0, y1);
            cand = mx >= -1e-3f;
            allIn = mn > 1e-3f;
            x0 = gxBC * pxlo; x1 = gxBC * pxhi; y0 = gyBC * pylo; y1 = gyBC * pyhi;
            mx = cBC + fmaxf(x0, x1) + fmaxf(y0, y1);
            mn = cBC + fminf(x0, x1) + fminf(y0, y1);
            cand = cand && (mx >= -1e-3f);
            allIn = allIn && (mn > 1e-3f);
            x0 = gxCA * pxlo; x1 = gxCA * pxhi; y0 = gyCA * pylo; y1 = gyCA * pyhi;
            mx = cCA + fmaxf(x0, x1) + fmaxf(y0, y1);
            mn = cCA + fminf(x0, x1) + fminf(y0, y1);
            cand = cand && (mx >= -1e-3f);
            allIn = allIn && (mn > 1e-3f);
        }

        bool full = (bb0 <= i0) && (bb2 >= i0 + 16) &&
                    (bb1 <= j0) && (bb3 >= j0 + 16);
        vIF[r] = cand && allIn && full;     // interior, bbox covers tile
        vIP[r] = cand && allIn && !full;    // interior, bbox test needed
        vEX[r] = cand && !allIn;            // exact edge eval needed

        unsigned long long mA = __ballot(vIF[r]);
        unsigned long long mB = __ballot(vIP[r]);
        unsigned long long mC = __ballot(vEX[r]);
        if (lane == 0) { smA[r * 4 + wv] = mA; smB[r * 4 + wv] = mB; smC[r * 4 + wv] = mC; }
    }

    for (int off = 32; off; off >>= 1) zm = fminf(zm, __shfl_xor(zm, off));
    if (lane == 0) sred[wv] = zm;
    __syncthreads();
    const float zmin = fminf(fminf(sred[0], sred[1]), fminf(sred[2], sred[3]));

    // ---- phase 2: ordered scatter into 3 compacted segments ----
    int bA[8], bB[8], bC[8], c = 0;
#pragma unroll
    for (int g = 0; g < 8; ++g) { bA[g] = c; c += __popcll(smA[g]); }
    const int cntA = c;
#pragma unroll
    for (int g = 0; g < 8; ++g) { bB[g] = c; c += __popcll(smB[g]); }
    const int cntB = c;
#pragma unroll
    for (int g = 0; g < 8; ++g) { bC[g] = c; c += __popcll(smC[g]); }
    const int cntC = c;

#pragma unroll
    for (int r = 0; r < 2; ++r) {
        if (vIF[r] || vIP[r] || vEX[r]) {
            const int g = r * 4 + wv;
            const int t = tid + r * 256;
            int pos;
            if (vIF[r])      pos = bA[g] + __popcll(smA[g] & lt);
            else if (vIP[r]) pos = bB[g] + __popcll(smB[g] & lt);
            else             pos = bC[g] + __popcll(smC[g] & lt);

            float a0 = va0[r], a1 = va1[r], b0 = vb0[r], b1 = vb1[r];
            float c0 = vc0[r], c1 = vc1[r];
            float rsw = __fdiv_rn(1.0f, vsw[r]);
            float k1 = (va2[r] - vc2[r]) * rsw;
            float k2 = (vb2[r] - vc2[r]) * rsw;
            float cAB = a0 * b1 - a1 * b0, gxAB = a1 - b1, gyAB = b0 - a0;
            float cBC = b0 * c1 - b1 * c0, gxBC = b1 - c1, gyBC = c0 - b0;
            float zc = vc2[r] + k1 * cAB + k2 * cBC;
            float zx = k1 * gxAB + k2 * gxBC;
            float zy = k1 * gyAB + k2 * gyBC;
            szp[pos] = make_float4(zc, zx, zy, __int_as_float(t));
            if (!vIF[r]) sbb[pos] = make_int4(vx0[r], vy0[r], vx1[r], vy1[r]);
            if (vEX[r]) {
                sv0[pos] = make_float4(a0, a1, b0, b1);
                sv1[pos] = make_float2(c0, c1);
            }
        }
    }
    __syncthreads();

    // ---- phase 3: per-pixel loop, 1 pixel/thread, 3 segments ----
    const int j = j0 + tx;
    const int i = i0 + ty;
    const float px = lin_at(i);
    const float py = lin_at(j);

    float best = zmin;
    float bf = __int_as_float(-1);

    // S1: interior + full bbox: z-plane only.
#pragma unroll 4
    for (int k = 0; k < cntA; ++k) {
        float4 zp = szp[k];
        float z = fmaf(zp.y, px, fmaf(zp.z, py, zp.x));
        if (z >= best) { best = z; bf = zp.w; }
    }
    // S2: interior + partial bbox.
#pragma unroll 4
    for (int k = cntA; k < cntB; ++k) {
        float4 zp = szp[k];
        int4 bb = sbb[k];
        float z = fmaf(zp.y, px, fmaf(zp.z, py, zp.x));
        bool in = (i >= bb.x) & (i < bb.z) & (j >= bb.y) & (j < bb.w);
        if (in & (z >= best)) { best = z; bf = zp.w; }
    }
    // S3: exact edge evaluation (reference op order) + bbox.
#pragma unroll 2
    for (int k = cntB; k < cntC; ++k) {
        float4 zp = szp[k];
        float4 f0 = sv0[k];
        float2 f1 = sv1[k];
        int4 bb = sbb[k];
        float dax = f0.x - px, day = f0.y - py;
        float dbx = f0.z - px, dby = f0.w - py;
        float dcx = f1.x - px, dcy = f1.y - py;
        float pAB = dax * dby - day * dbx;
        float pBC = dbx * dcy - dby * dcx;
        float pCA = dcx * day - dcy * dax;
        bool cov = (pAB > 0.0f) & (pBC > 0.0f) & (pCA > 0.0f) &
                   (i >= bb.x) & (i < bb.z) & (j >= bb.y) & (j < bb.w);
        float z = fmaf(zp.y, px, fmaf(zp.z, py, zp.x));
        if (cov & (z >= best)) { best = z; bf = zp.w; }
    }

    // ---- epilogue: bit-exact shade of winner ----
    ((float4*)out)[i * SIZE + j] = shade(tris, __float_as_int(bf), px, py);
}

extern "C" void kernel_launch(void* const* d_in, const int* in_sizes, int n_in,
                              void* d_out, int out_size, void* d_ws, size_t ws_size,
                              hipStream_t stream) {
    const float* tris = (const float*)d_in[0];
    float* out = (float*)d_out;
    dim3 grid(SIZE / 16, SIZE / 16, 1);
    dim3 block(16, 16, 1);
    render_kernel<<<grid, block, 0, stream>>>(tris, out);
}

// Round 7
// 12.447 us; speedup vs baseline: 1.8756x; 1.3100x over previous
//
#include <hip/hip_runtime.h>

#define SIZE 512
#define NTRI 512

#pragma clang fp contract(off)

__device__ __forceinline__ float lin_at(int i) {
    // Replicates jnp.linspace(-1, 1, 512): for i < 511,
    // s = i/511 (f32 correctly-rounded div), out = (-1)*(1-s) + 1*s = s - (1-s).
    // Endpoint i == 511 is exactly 1.0.
    if (i == SIZE - 1) return 1.0f;
    float s = __fdiv_rn((float)i, 511.0f);
    float u = 1.0f - s;
    return s - u;
}

// Bit-exact reference epilogue for the winning triangle (true division, exact op order).
__device__ __forceinline__ float4 shade(const float* __restrict__ tris, int bi,
                                        float px, float py) {
#pragma clang fp contract(off)
    if (bi < 0) return make_float4(0.0f, 0.0f, 0.0f, 0.0f);
    const float* p = tris + bi * 9;
    float a0 = p[0], a1 = p[1], a2 = p[2];
    float b0 = p[3], b1 = p[4], b2 = p[5];
    float c0 = p[6], c1 = p[7], c2 = p[8];
    float w = (b0 - a0) * (c1 - a1) - (b1 - a1) * (c0 - a0);
    float sw = (fabsf(w) > 1e-8f) ? w : 1.0f;
    float dax = a0 - px, day = a1 - py;
    float dbx = b0 - px, dby = b1 - py;
    float dcx = c0 - px, dcy = c1 - py;
    float pAB = dax * dby - day * dbx;
    float pBC = dbx * dcy - dby * dcx;
    float w1 = __fdiv_rn(pAB, sw);
    float w2 = __fdiv_rn(pBC, sw);
    float w3 = 1.0f - w1 - w2;
    float x = (w1 * a0 + w2 * b0) + w3 * c0;
    float y = (w1 * a1 + w2 * b1) + w3 * c1;
    float z = (w1 * a2 + w2 * b2) + w3 * c2;
    return make_float4(x, y, z, 1.0f);
}

__global__ __launch_bounds__(256) void render_kernel(const float* __restrict__ tris,
                                                     float* __restrict__ out) {
#pragma clang fp contract(off)
    __shared__ float4 szp[NTRI];   // zc, zx, zy, bitcast(t)   (all classes, compacted)
    __shared__ int4   sbb[NTRI];   // int bbox                 (classes IP, EX)
    __shared__ float4 sv0[NTRI];   // a0, a1, b0, b1           (class EX)
    __shared__ float2 sv1[NTRI];   // c0, c1                   (class EX)
    __shared__ unsigned long long smA[8], smB[8], smC[8];
    __shared__ float sredz[4], sredm[4];

    const int tx = threadIdx.x;          // 0..15 -> j offset
    const int ty = threadIdx.y;          // 0..15 -> i offset
    const int tid = ty * 16 + tx;        // 0..255
    const int lane = tid & 63, wv = tid >> 6;
    const unsigned long long lt = (1ull << lane) - 1ull;

    const int i0 = blockIdx.y * 16;
    const int j0 = blockIdx.x * 16;

    const float pxlo = lin_at(i0), pxhi = lin_at(i0 + 15);
    const float pylo = lin_at(j0), pyhi = lin_at(j0 + 15);

    // ---- phase 1: 2 tris/thread: preprocess, cull, classify, z-bounds ----
    float va0[2], va1[2], vb0[2], vb1[2], vc0[2], vc1[2];
    float vzc[2], vzx[2], vzy[2], vtzx[2];
    int   vx0[2], vy0[2], vx1[2], vy1[2];
    bool  vIF[2], vIP[2], vEX[2];

    float zm = 1e30f;       // global z-min (background init)
    float mloc = -1e30f;    // max over full-coverage candidates of tile-zmin
#pragma unroll
    for (int r = 0; r < 2; ++r) {
        const int t = tid + r * 256;
        const float* p = tris + t * 9;
        float a0 = p[0], a1 = p[1], a2 = p[2];
        float b0 = p[3], b1 = p[4], b2 = p[5];
        float c0 = p[6], c1 = p[7], c2 = p[8];
        va0[r] = a0; va1[r] = a1;
        vb0[r] = b0; vb1[r] = b1;
        vc0[r] = c0; vc1[r] = c1;

        zm = fminf(zm, fminf(a2, fminf(b2, c2)));

        float w = (b0 - a0) * (c1 - a1) - (b1 - a1) * (c0 - a0);
        bool vw = fabsf(w) > 1e-8f;
        float sw = vw ? w : 1.0f;

        float lox = fminf(fminf(a0, b0), c0);
        float loy = fminf(fminf(a1, b1), c1);
        float hix = fmaxf(fmaxf(a0, b0), c0);
        float hiy = fmaxf(fmaxf(a1, b1), c1);
        int bb0 = (int)((fminf(fmaxf(lox, -1.0f), 1.0f) + 1.0f) * 0.5f * 512.0f);
        int bb1 = (int)((fminf(fmaxf(loy, -1.0f), 1.0f) + 1.0f) * 0.5f * 512.0f);
        int bb2 = (int)((fminf(fmaxf(hix, -1.0f), 1.0f) + 1.0f) * 0.5f * 512.0f);
        int bb3 = (int)((fminf(fmaxf(hiy, -1.0f), 1.0f) + 1.0f) * 0.5f * 512.0f);
        vx0[r] = bb0; vy0[r] = bb1; vx1[r] = bb2; vy1[r] = bb3;

        // Winding cull (pAB+pBC+pCA == w algebraically) + bbox-vs-tile cull.
        bool cand = vw && (w > -1e-4f) &&
                    (bb0 < i0 + 16) && (bb2 > i0) &&
                    (bb1 < j0 + 16) && (bb3 > j0);

        // Edge consts (needed for rect tests AND z-plane).
        float cAB = a0 * b1 - a1 * b0, gxAB = a1 - b1, gyAB = b0 - a0;
        float cBC = b0 * c1 - b1 * c0, gxBC = b1 - c1, gyBC = c0 - b0;
        float cCA = c0 * a1 - c1 * a0, gxCA = c1 - a1, gyCA = a0 - c0;

        // Edge-vs-tile rect: max over rect < -1e-3 -> cull; min > +1e-3 ->
        // edge certainly positive at every tile pixel (guard >> 1.5e-5 fp bound).
        bool allIn = false;
        if (cand) {
            float x0, x1, y0, y1, mx, mn;
            x0 = gxAB * pxlo; x1 = gxAB * pxhi; y0 = gyAB * pylo; y1 = gyAB * pyhi;
            mx = cAB + fmaxf(x0, x1) + fmaxf(y0, y1);
            mn = cAB + fminf(x0, x1) + fminf(y0, y1);
            cand = mx >= -1e-3f;
            allIn = mn > 1e-3f;
            x0 = gxBC * pxlo; x1 = gxBC * pxhi; y0 = gyBC * pylo; y1 = gyBC * pyhi;
            mx = cBC + fmaxf(x0, x1) + fmaxf(y0, y1);
            mn = cBC + fminf(x0, x1) + fminf(y0, y1);
            cand = cand && (mx >= -1e-3f);
            allIn = allIn && (mn > 1e-3f);
            x0 = gxCA * pxlo; x1 = gxCA * pxhi; y0 = gyCA * pylo; y1 = gyCA * pyhi;
            mx = cCA + fmaxf(x0, x1) + fmaxf(y0, y1);
            mn = cCA + fminf(x0, x1) + fminf(y0, y1);
            cand = cand && (mx >= -1e-3f);
            allIn = allIn && (mn > 1e-3f);
        }

        // z-plane (selection-only precision: fast rcp; shade recomputes exactly).
        float rsw = __builtin_amdgcn_rcpf(sw);
        float k1 = (a2 - c2) * rsw;
        float k2 = (b2 - c2) * rsw;
        float zc = c2 + k1 * cAB + k2 * cBC;
        float zx = k1 * gxAB + k2 * gxBC;
        float zy = k1 * gyAB + k2 * gyBC;
        vzc[r] = zc; vzx[r] = zx; vzy[r] = zy;

        // Certified z-bounds of the plane over the tile rect.
        float zxl = zx * pxlo, zxh = zx * pxhi;
        float zyl = zy * pylo, zyh = zy * pyhi;
        float tzmin = zc + fminf(zxl, zxh) + fminf(zyl, zyh);
        float tzmax = zc + fmaxf(zxl, zxh) + fmaxf(zyl, zyh);
        vtzx[r] = tzmax;

        bool full = (bb0 <= i0) && (bb2 >= i0 + 16) &&
                    (bb1 <= j0) && (bb3 >= j0 + 16);
        vIF[r] = cand && allIn && full;     // covers every tile pixel
        vIP[r] = cand && allIn && !full;
        vEX[r] = cand && !allIn;

        // Hierarchical-Z basis: only full-coverage candidates dominate everywhere.
        if (vIF[r]) mloc = fmaxf(mloc, tzmin);
    }

    // Joint block reductions: zmin (min) and M (max of IF tile-zmins). Exact ops.
    for (int off = 32; off; off >>= 1) {
        zm = fminf(zm, __shfl_xor(zm, off));
        mloc = fmaxf(mloc, __shfl_xor(mloc, off));
    }
    if (lane == 0) { sredz[wv] = zm; sredm[wv] = mloc; }
    __syncthreads();
    const float zmin = fminf(fminf(sredz[0], sredz[1]), fminf(sredz[2], sredz[3]));
    const float M = fmaxf(fmaxf(sredm[0], sredm[1]), fmaxf(sredm[2], sredm[3]));
    // Any candidate with tzmax < max(M, zmin) - 1e-4 can never win a pixel
    // (dominating IF plane >= M - 2e-6 everywhere; guard >> fp discrepancy).
    const float cullb = fmaxf(M, zmin) - 1e-4f;

    // ---- apply hier-Z cull, then ballots ----
#pragma unroll
    for (int r = 0; r < 2; ++r) {
        bool keep = vtzx[r] >= cullb;
        vIF[r] &= keep; vIP[r] &= keep; vEX[r] &= keep;
        unsigned long long mA = __ballot(vIF[r]);
        unsigned long long mB = __ballot(vIP[r]);
        unsigned long long mC = __ballot(vEX[r]);
        if (lane == 0) { smA[r * 4 + wv] = mA; smB[r * 4 + wv] = mB; smC[r * 4 + wv] = mC; }
    }
    __syncthreads();

    // ---- phase 2: ordered scatter into 3 compacted segments ----
    int bA[8], bB[8], bC[8], c = 0;
#pragma unroll
    for (int g = 0; g < 8; ++g) { bA[g] = c; c += __popcll(smA[g]); }
    const int cntA = c;
#pragma unroll
    for (int g = 0; g < 8; ++g) { bB[g] = c; c += __popcll(smB[g]); }
    const int cntB = c;
#pragma unroll
    for (int g = 0; g < 8; ++g) { bC[g] = c; c += __popcll(smC[g]); }
    const int cntC = c;

#pragma unroll
    for (int r = 0; r < 2; ++r) {
        if (vIF[r] || vIP[r] || vEX[r]) {
            const int g = r * 4 + wv;
            const int t = tid + r * 256;
            int pos;
            if (vIF[r])      pos = bA[g] + __popcll(smA[g] & lt);
            else if (vIP[r]) pos = bB[g] + __popcll(smB[g] & lt);
            else             pos = bC[g] + __popcll(smC[g] & lt);

            szp[pos] = make_float4(vzc[r], vzx[r], vzy[r], __int_as_float(t));
            if (!vIF[r]) sbb[pos] = make_int4(vx0[r], vy0[r], vx1[r], vy1[r]);
            if (vEX[r]) {
                sv0[pos] = make_float4(va0[r], va1[r], vb0[r], vb1[r]);
                sv1[pos] = make_float2(vc0[r], vc1[r]);
            }
        }
    }
    __syncthreads();

    // ---- phase 3: per-pixel loop, 1 pixel/thread, 3 segments ----
    const int j = j0 + tx;
    const int i = i0 + ty;
    const float px = lin_at(i);
    const float py = lin_at(j);

    float best = zmin;
    float bf = __int_as_float(-1);

    // S1: interior + full bbox: z-plane only.
#pragma unroll 4
    for (int k = 0; k < cntA; ++k) {
        float4 zp = szp[k];
        float z = fmaf(zp.y, px, fmaf(zp.z, py, zp.x));
        if (z >= best) { best = z; bf = zp.w; }
    }
    // S2: interior + partial bbox.
#pragma unroll 4
    for (int k = cntA; k < cntB; ++k) {
        float4 zp = szp[k];
        int4 bb = sbb[k];
        float z = fmaf(zp.y, px, fmaf(zp.z, py, zp.x));
        bool in = (i >= bb.x) & (i < bb.z) & (j >= bb.y) & (j < bb.w);
        if (in & (z >= best)) { best = z; bf = zp.w; }
    }
    // S3: exact edge evaluation (reference op order) + bbox.
#pragma unroll 2
    for (int k = cntB; k < cntC; ++k) {
        float4 zp = szp[k];
        float4 f0 = sv0[k];
        float2 f1 = sv1[k];
        int4 bb = sbb[k];
        float dax = f0.x - px, day = f0.y - py;
        float dbx = f0.z - px, dby = f0.w - py;
        float dcx = f1.x - px, dcy = f1.y - py;
        float pAB = dax * dby - day * dbx;
        float pBC = dbx * dcy - dby * dcx;
        float pCA = dcx * day - dcy * dax;
        bool cov = (pAB > 0.0f) & (pBC > 0.0f) & (pCA > 0.0f) &
                   (i >= bb.x) & (i < bb.z) & (j >= bb.y) & (j < bb.w);
        float z = fmaf(zp.y, px, fmaf(zp.z, py, zp.x));
        if (cov & (z >= best)) { best = z; bf = zp.w; }
    }

    // ---- epilogue: bit-exact shade of winner ----
    ((float4*)out)[i * SIZE + j] = shade(tris, __float_as_int(bf), px, py);
}

extern "C" void kernel_launch(void* const* d_in, const int* in_sizes, int n_in,
                              void* d_out, int out_size, void* d_ws, size_t ws_size,
                              hipStream_t stream) {
    const float* tris = (const float*)d_in[0];
    float* out = (float*)d_out;
    dim3 grid(SIZE / 16, SIZE / 16, 1);
    dim3 block(16, 16, 1);
    render_kernel<<<grid, block, 0, stream>>>(tris, out);
}